// Round 1
// baseline (526.207 us; speedup 1.0000x reference)
//
#include <hip/hip_runtime.h>
#include <math.h>

#define BB 16
#define SS 4096
#define HH 1024
#define CC 64

typedef __attribute__((ext_vector_type(4))) float f32x4;
typedef __attribute__((ext_vector_type(8))) short s16x8;
typedef __attribute__((ext_vector_type(4))) unsigned int u32x4;

__device__ __forceinline__ ushort f2bf(float x) {
    union { float f; unsigned u; } un; un.f = x;
    unsigned r = (un.u + 0x7FFFu + ((un.u >> 16) & 1u)) >> 16;
    return (ushort)r;
}
__device__ __forceinline__ float bf2f(ushort h) {
    union { unsigned u; float f; } un; un.u = ((unsigned)h) << 16; return un.f;
}

// pack the high 16 bits of two dwords: result = {lo16 = v0>>16, hi16 = v1>>16}
__device__ __forceinline__ unsigned hipack(unsigned v1, unsigned v0) {
    return __builtin_amdgcn_perm(v1, v0, 0x07060302u);
}

// split 8 fp32 -> bf16 hi (round-half-up) + bf16 lo (exact residual, truncated)
__device__ __forceinline__ void cvt8(f32x4 f0, f32x4 f1, s16x8& hi, s16x8& lo) {
    u32x4 u0 = __builtin_bit_cast(u32x4, f0);
    u32x4 u1 = __builtin_bit_cast(u32x4, f1);
    u32x4 b0 = u0 + 0x8000u;
    u32x4 b1 = u1 + 0x8000u;
    f32x4 m0 = __builtin_bit_cast(f32x4, b0 & 0xFFFF0000u);
    f32x4 m1 = __builtin_bit_cast(f32x4, b1 & 0xFFFF0000u);
    u32x4 r0 = __builtin_bit_cast(u32x4, f0 - m0);
    u32x4 r1 = __builtin_bit_cast(u32x4, f1 - m1);
    u32x4 h = { hipack(b0.y, b0.x), hipack(b0.w, b0.z),
                hipack(b1.y, b1.x), hipack(b1.w, b1.z) };
    u32x4 l = { hipack(r0.y, r0.x), hipack(r0.w, r0.z),
                hipack(r1.y, r1.x), hipack(r1.w, r1.z) };
    hi = __builtin_bit_cast(s16x8, h);
    lo = __builtin_bit_cast(s16x8, l);
}

// ---------------- prep: querys -> hi/lo bf16
__global__ __launch_bounds__(256) void prep_querys_kernel(
    const float* __restrict__ q, ushort* __restrict__ qhi, ushort* __restrict__ qlo)
{
    const int i4 = blockIdx.x * 256 + threadIdx.x;   // float4 index, 16384 total
    const float4 v = ((const float4*)q)[i4];
    ushort4 h, l;
    h.x = f2bf(v.x); l.x = f2bf(v.x - bf2f(h.x));
    h.y = f2bf(v.y); l.y = f2bf(v.y - bf2f(h.y));
    h.z = f2bf(v.z); l.z = f2bf(v.z - bf2f(h.z));
    h.w = f2bf(v.w); l.w = f2bf(v.w - bf2f(h.w));
    ((ushort4*)qhi)[i4] = h;
    ((ushort4*)qlo)[i4] = l;
}

// ---------------- scores[b][c][s]: barrier-free, LDS-free reg-streamed split-bf16 MFMA.
// 128s x 64c tile/block, 4 waves, each wave 32s (mt=2). Also emits hid_hi (bf16 of hidden).
__global__ __launch_bounds__(256) void scores_kernel(
    const float* __restrict__ hidden, const ushort* __restrict__ qhi,
    const ushort* __restrict__ qlo, float* __restrict__ scores,
    ushort* __restrict__ hid_hi)
{
    const int b  = blockIdx.y;
    const int s0 = blockIdx.x * 128;
    const int t  = threadIdx.x;
    const int w = t >> 6, lane = t & 63, col = lane & 15, quad = lane >> 4;

    // A-fragment rows owned by this lane (m = lane&15, k = quad*8..+8)
    const int r0 = s0 + w * 32 + col;
    const int r1 = r0 + 16;
    const float* a0p = hidden + ((size_t)b * SS + r0) * HH + quad * 8;
    const float* a1p = hidden + ((size_t)b * SS + r1) * HH + quad * 8;
    ushort* h0p = hid_hi + ((size_t)b * SS + r0) * HH + quad * 8;
    ushort* h1p = hid_hi + ((size_t)b * SS + r1) * HH + quad * 8;
    const ushort* qbh = qhi + (size_t)col * HH + quad * 8;
    const ushort* qbl = qlo + (size_t)col * HH + quad * 8;

    f32x4 acc[2][4];
#pragma unroll
    for (int i = 0; i < 2; ++i)
#pragma unroll
        for (int j = 0; j < 4; ++j) acc[i][j] = (f32x4){0.f, 0.f, 0.f, 0.f};

    f32x4 Aa0, Aa1, Aa2, Aa3, Ab0, Ab1, Ab2, Ab3;

#define LOADA(P0, P1, P2, P3, K) do { \
    P0 = *(const f32x4*)(a0p + (K));     P1 = *(const f32x4*)(a0p + (K) + 4); \
    P2 = *(const f32x4*)(a1p + (K));     P3 = *(const f32x4*)(a1p + (K) + 4); } while (0)

#define SCOMP(P0, P1, P2, P3, K) do { \
    s16x8 ah0, al0, ah1, al1; \
    cvt8(P0, P1, ah0, al0); \
    cvt8(P2, P3, ah1, al1); \
    *(s16x8*)(h0p + (K)) = ah0; \
    *(s16x8*)(h1p + (K)) = ah1; \
    _Pragma("unroll") \
    for (int nt = 0; nt < 4; ++nt) { \
        const s16x8 bh = *(const s16x8*)(qbh + nt * 16 * HH + (K)); \
        const s16x8 bl = *(const s16x8*)(qbl + nt * 16 * HH + (K)); \
        acc[0][nt] = __builtin_amdgcn_mfma_f32_16x16x32_bf16(ah0, bh, acc[0][nt], 0, 0, 0); \
        acc[0][nt] = __builtin_amdgcn_mfma_f32_16x16x32_bf16(ah0, bl, acc[0][nt], 0, 0, 0); \
        acc[0][nt] = __builtin_amdgcn_mfma_f32_16x16x32_bf16(al0, bh, acc[0][nt], 0, 0, 0); \
        acc[1][nt] = __builtin_amdgcn_mfma_f32_16x16x32_bf16(ah1, bh, acc[1][nt], 0, 0, 0); \
        acc[1][nt] = __builtin_amdgcn_mfma_f32_16x16x32_bf16(ah1, bl, acc[1][nt], 0, 0, 0); \
        acc[1][nt] = __builtin_amdgcn_mfma_f32_16x16x32_bf16(al1, bh, acc[1][nt], 0, 0, 0); \
    } } while (0)

    LOADA(Aa0, Aa1, Aa2, Aa3, 0);
    for (int k0 = 0; k0 < HH; k0 += 64) {
        LOADA(Ab0, Ab1, Ab2, Ab3, k0 + 32);
        SCOMP(Aa0, Aa1, Aa2, Aa3, k0);
        if (k0 + 64 < HH) LOADA(Aa0, Aa1, Aa2, Aa3, k0 + 64);
        SCOMP(Ab0, Ab1, Ab2, Ab3, k0 + 32);
    }
#undef LOADA
#undef SCOMP

    // C/D: col=lane&15 -> c (n), row=quad*4+reg -> s (m)
#pragma unroll
    for (int mt = 0; mt < 2; ++mt)
#pragma unroll
        for (int nt = 0; nt < 4; ++nt) {
            const int c = nt * 16 + col;
            const int s = s0 + w * 32 + mt * 16 + quad * 4;
            *(f32x4*)&scores[((size_t)(b * CC + c)) * SS + s] = acc[mt][nt];
        }
}

// ---------------- softmax over s, writes bf16 factor
__global__ __launch_bounds__(256) void softmax_kernel(
    const float* __restrict__ scores, ushort* __restrict__ factor)
{
    const float* p = scores + (size_t)blockIdx.x * SS;
    ushort* f = factor + (size_t)blockIdx.x * SS;
    const int t = threadIdx.x;
    float4 v[4];
    float m = -3.0e38f;
#pragma unroll
    for (int i = 0; i < 4; ++i) {
        v[i] = *(const float4*)&p[t * 4 + i * 1024];
        m = fmaxf(m, fmaxf(fmaxf(v[i].x, v[i].y), fmaxf(v[i].z, v[i].w)));
    }
#pragma unroll
    for (int off = 1; off < 64; off <<= 1) m = fmaxf(m, __shfl_xor(m, off));
    __shared__ float redm[4];
    __shared__ float reds[4];
    const int wave = t >> 6, lane = t & 63;
    if (lane == 0) redm[wave] = m;
    __syncthreads();
    m = fmaxf(fmaxf(redm[0], redm[1]), fmaxf(redm[2], redm[3]));

    float sum = 0.0f;
#pragma unroll
    for (int i = 0; i < 4; ++i) {
        v[i].x = __expf(v[i].x - m); v[i].y = __expf(v[i].y - m);
        v[i].z = __expf(v[i].z - m); v[i].w = __expf(v[i].w - m);
        sum += (v[i].x + v[i].y) + (v[i].z + v[i].w);
    }
#pragma unroll
    for (int off = 1; off < 64; off <<= 1) sum += __shfl_xor(sum, off);
    if (lane == 0) reds[wave] = sum;
    __syncthreads();
    sum = (reds[0] + reds[1]) + (reds[2] + reds[3]);
    const float inv = 1.0f / sum;
#pragma unroll
    for (int i = 0; i < 4; ++i) {
        ushort4 o;
        o.x = f2bf(v[i].x * inv); o.y = f2bf(v[i].y * inv);
        o.z = f2bf(v[i].z * inv); o.w = f2bf(v[i].w * inv);
        ((ushort4*)f)[t + i * 256] = o;
    }
}

// ---------------- pool: parts[ks][b][c][h], barrier-free, LDS-free. Reads bf16 hid_hi.
// 64c x 64h tile/block, split-4 over S. B-frags assembled from scalar ushort loads.
__global__ __launch_bounds__(256) void pool_kernel(
    const ushort* __restrict__ hid_hi, const ushort* __restrict__ factor,
    float* __restrict__ parts)
{
    const int b  = blockIdx.y;
    const int h0 = blockIdx.x * 64;
    const int ks = blockIdx.z;
    const int sbeg = ks * (SS / 4);
    const int t = threadIdx.x;
    const int w = t >> 6, lane = t & 63, col = lane & 15, quad = lane >> 4;

    f32x4 acc[4];
#pragma unroll
    for (int j = 0; j < 4; ++j) acc[j] = (f32x4){0.f, 0.f, 0.f, 0.f};

    // A-frag (factor): m = c = w*16+col, k = s (contiguous)
    const ushort* fptr = factor + ((size_t)(b * CC + w * 16 + col)) * SS + sbeg + quad * 8;
    // B-frag (hidden^T): n = h = h0+nt*16+col, k = s -> scalar loads at row stride HH
    const ushort* hp = hid_hi + ((size_t)b * SS + sbeg + quad * 8) * HH + h0 + col;

    ushort ra[4][8], rb[4][8];
    s16x8 faA, faB;

#define PLOAD(R, FA, SC) do { \
    FA = *(const s16x8*)(fptr + (SC)); \
    _Pragma("unroll") for (int nt = 0; nt < 4; ++nt) \
    _Pragma("unroll") for (int j = 0; j < 8; ++j) \
        R[nt][j] = hp[(size_t)((SC) + j) * HH + nt * 16]; } while (0)

#define PCOMP(R, FA) do { \
    _Pragma("unroll") for (int nt = 0; nt < 4; ++nt) { \
        u32x4 d = { (unsigned)R[nt][0] | ((unsigned)R[nt][1] << 16), \
                    (unsigned)R[nt][2] | ((unsigned)R[nt][3] << 16), \
                    (unsigned)R[nt][4] | ((unsigned)R[nt][5] << 16), \
                    (unsigned)R[nt][6] | ((unsigned)R[nt][7] << 16) }; \
        const s16x8 hb = __builtin_bit_cast(s16x8, d); \
        acc[nt] = __builtin_amdgcn_mfma_f32_16x16x32_bf16(FA, hb, acc[nt], 0, 0, 0); \
    } } while (0)

    PLOAD(ra, faA, 0);
    for (int sc = 0; sc < SS / 4; sc += 64) {
        PLOAD(rb, faB, sc + 32);
        PCOMP(ra, faA);
        if (sc + 64 < SS / 4) PLOAD(ra, faA, sc + 64);
        PCOMP(rb, faB);
    }
#undef PLOAD
#undef PCOMP

    float* dst = parts + (size_t)ks * (BB * CC * HH) + (size_t)b * (CC * HH);
#pragma unroll
    for (int nt = 0; nt < 4; ++nt) {
        const int h = h0 + nt * 16 + col;
#pragma unroll
        for (int r = 0; r < 4; ++r) {
            const int c = w * 16 + quad * 4 + r;
            dst[(size_t)c * HH + h] = acc[nt][r];
        }
    }
}

// ---------------- final reduce of 4 split-K partials
__global__ __launch_bounds__(256) void reduce4_kernel(
    const float* __restrict__ parts, float* __restrict__ out)
{
    const int i = blockIdx.x * 256 + threadIdx.x;   // float4 index
    const float4* p = (const float4*)parts;
    const float4 a = p[i];
    const float4 b = p[i + 262144];
    const float4 c = p[i + 524288];
    const float4 d = p[i + 786432];
    float4 r;
    r.x = (a.x + b.x) + (c.x + d.x);
    r.y = (a.y + b.y) + (c.y + d.y);
    r.z = (a.z + b.z) + (c.z + d.z);
    r.w = (a.w + b.w) + (c.w + d.w);
    ((float4*)out)[i] = r;
}

extern "C" void kernel_launch(void* const* d_in, const int* in_sizes, int n_in,
                              void* d_out, int out_size, void* d_ws, size_t ws_size,
                              hipStream_t stream)
{
    const float* hidden = (const float*)d_in[0];   // [16,4096,1024] fp32
    const float* querys = (const float*)d_in[1];   // [64,1024] fp32
    float* out = (float*)d_out;

    float*  scores = (float*)d_ws;                           // 16 MiB [0,16M)
    float*  parts  = (float*)d_ws;                           // aliases scores (pool phase)
    ushort* factor = (ushort*)((char*)d_ws + (16u << 20));   // 8 MiB [16M,24M)
    ushort* qhi    = (ushort*)((char*)d_ws + (24u << 20));   // 128 KiB
    ushort* qlo    = qhi + CC * HH;                          // 128 KiB
    ushort* hid_hi = (ushort*)((char*)d_ws + (32u << 20));   // 128 MiB [32M,160M)

    prep_querys_kernel<<<dim3(CC * HH / 1024), 256, 0, stream>>>(querys, qhi, qlo);
    scores_kernel<<<dim3(SS / 128, BB), 256, 0, stream>>>(hidden, qhi, qlo, scores, hid_hi);
    softmax_kernel<<<dim3(BB * CC), 256, 0, stream>>>(scores, factor);
    pool_kernel<<<dim3(HH / 64, BB, 4), 256, 0, stream>>>(hid_hi, factor, parts);
    reduce4_kernel<<<dim3(1024), 256, 0, stream>>>(parts, out);
}